// Round 1
// baseline (823.326 us; speedup 1.0000x reference)
//
#include <hip/hip_runtime.h>
#include <hip/hip_fp16.h>

typedef _Float16 half_t;
typedef _Float16 f16x8 __attribute__((ext_vector_type(8)));
typedef _Float16 f16x4 __attribute__((ext_vector_type(4)));
typedef float f32x4 __attribute__((ext_vector_type(4)));

#define SEQ 4096
#define DDIM 1024
#define NBATCH 4

// async global->LDS, 16B per lane. LDS dest is wave-uniform base + lane*16,
// so the per-lane lds pointer MUST be base + lane*16 in wave-lane order.
__device__ __forceinline__ void gload16(const half_t* g, half_t* l) {
  __builtin_amdgcn_global_load_lds((const __attribute__((address_space(1))) void*)g,
                                   (__attribute__((address_space(3))) void*)l, 16, 0, 0);
}

// ---------------- fp32 -> fp16 elementwise convert ----------------
__global__ __launch_bounds__(256) void conv_f16(const float* __restrict__ src,
                                                half_t* __restrict__ dst) {
  int i = blockIdx.x * 256 + threadIdx.x;
  float4 x = ((const float4*)src)[i];
  f16x4 o = {(half_t)x.x, (half_t)x.y, (half_t)x.z, (half_t)x.w};
  *(f16x4*)(dst + (size_t)i * 4) = o;
}

// ---------------- enc [b][e][d] fp32 -> encT [b][d][e] fp16 ----------------
__global__ __launch_bounds__(256) void transpose_f16(const float* __restrict__ src,
                                                     half_t* __restrict__ dst) {
  __shared__ float tile[32][33];
  int b = blockIdx.z;
  int e0 = blockIdx.x * 32, d0 = blockIdx.y * 32;
  const float* s = src + (size_t)b * SEQ * DDIM;
  half_t* dt = dst + (size_t)b * DDIM * SEQ;
  int tx = threadIdx.x & 31, ty = threadIdx.x >> 5;
#pragma unroll
  for (int i = 0; i < 4; i++) {
    int e = e0 + ty + i * 8;
    tile[ty + i * 8][tx] = s[(size_t)e * DDIM + d0 + tx];
  }
  __syncthreads();
#pragma unroll
  for (int i = 0; i < 4; i++) {
    int d = d0 + ty + i * 8;
    dt[(size_t)d * SEQ + e0 + tx] = (half_t)tile[tx][ty + i * 8];
  }
}

// ---------------- fp16 BT GEMM: C[M][N] fp32 = A[M][K] * B[N][K]^T ----------
// m97 structure: 128x128 tile, BK=64, global_load_lds width-16 staging,
// unpadded LDS + XOR chunk swizzle (slot = chunk ^ (row&7)) for conflict-free
// ds_read_b128 fragments. 256 thr = 4 waves (2x2 of 64x64).
// Generalized: blockIdx.z selects batch (sA/sB/sC elem strides) OR split-K
// chunk (sA=sB=kc, sC=0, atom=1 -> global_atomic_add_f32 epilogue).
// K = row stride in elements; kc = K-extent this block iterates.
#define BM 128
#define BN 128
#define BK 64

__global__ __launch_bounds__(256) void gemm_f16(const half_t* __restrict__ A,
                                                const half_t* __restrict__ B,
                                                float* __restrict__ C, int M, int N, int K,
                                                int kc, long sA, long sB, long sC, int atom) {
  A += (size_t)blockIdx.z * (size_t)sA;
  B += (size_t)blockIdx.z * (size_t)sB;
  C += (size_t)blockIdx.z * (size_t)sC;
  __shared__ __align__(16) half_t As[BM * BK];
  __shared__ __align__(16) half_t Bs[BN * BK];
  const int tid = threadIdx.x;
  const int bm = blockIdx.x, bn = blockIdx.y;
  const int wave = tid >> 6, lane = tid & 63;
  const int wm = (wave & 1) * 64, wn = (wave >> 1) * 64;
  const int mrow = lane & 15, quad = lane >> 4;

  f32x4 acc[4][4];
#pragma unroll
  for (int i = 0; i < 4; i++)
#pragma unroll
    for (int j = 0; j < 4; j++) acc[i][j] = {0.f, 0.f, 0.f, 0.f};

  const half_t* Ag = A + (size_t)(bm * BM) * K;
  const half_t* Bg = B + (size_t)(bn * BN) * K;

  // staging geometry: tile = 128 rows x 8 chunks(16B); cid = i*256 + tid
  // row = cid>>3, slot = cid&7, global chunk = slot ^ (row&7)
  for (int k0 = 0; k0 < kc; k0 += BK) {
#pragma unroll
    for (int i = 0; i < 4; i++) {
      int cid = i * 256 + tid;
      int row = cid >> 3, slot = cid & 7;
      int chunk = slot ^ (row & 7);
      gload16(Ag + (size_t)row * K + k0 + chunk * 8, &As[row * BK + slot * 8]);
      gload16(Bg + (size_t)row * K + k0 + chunk * 8, &Bs[row * BK + slot * 8]);
    }
    __builtin_amdgcn_s_waitcnt(0);
    __syncthreads();
#pragma unroll
    for (int ks = 0; ks < 2; ks++) {
      f16x8 af[4], bf[4];
#pragma unroll
      for (int i = 0; i < 4; i++) {
        int ra = wm + i * 16 + mrow;
        int rb = wn + i * 16 + mrow;
        int sa = (ks * 4 + quad) ^ (ra & 7);
        int sb = (ks * 4 + quad) ^ (rb & 7);
        af[i] = *(const f16x8*)(&As[ra * BK + sa * 8]);
        bf[i] = *(const f16x8*)(&Bs[rb * BK + sb * 8]);
      }
#pragma unroll
      for (int mi = 0; mi < 4; mi++)
#pragma unroll
        for (int ni = 0; ni < 4; ni++)
          acc[mi][ni] =
              __builtin_amdgcn_mfma_f32_16x16x32_f16(af[mi], bf[ni], acc[mi][ni], 0, 0, 0);
    }
    __syncthreads();
  }
  // epilogue: D[row=(quad*4+r)][col=lane&15] per 16x16 tile [measured m89/m91]
#pragma unroll
  for (int mi = 0; mi < 4; mi++) {
#pragma unroll
    for (int ni = 0; ni < 4; ni++) {
      int row0 = bm * BM + wm + mi * 16 + quad * 4;
      int col = bn * BN + wn + ni * 16 + mrow;
      float* Cp = C + (size_t)row0 * N + col;
      if (atom) {
#pragma unroll
        for (int r = 0; r < 4; r++) unsafeAtomicAdd(Cp + (size_t)r * N, acc[mi][ni][r]);
      } else {
#pragma unroll
        for (int r = 0; r < 4; r++) Cp[(size_t)r * N] = acc[mi][ni][r];
      }
    }
  }
}

// ---------------- row softmax: S[t][:] fp32 -> P[t][:] fp16 ----------------
__global__ __launch_bounds__(256) void softmax_rows(const float* __restrict__ S,
                                                    half_t* __restrict__ P) {
  const int row = blockIdx.x;
  const float4* Sr = (const float4*)(S + (size_t)row * SEQ);
  const int tid = threadIdx.x, lane = tid & 63, wave = tid >> 6;
  __shared__ float red[4];
  __shared__ float bc;
  float4 v[4];
  float m = -1e30f;
#pragma unroll
  for (int j = 0; j < 4; j++) {
    v[j] = Sr[tid + j * 256];
    m = fmaxf(m, fmaxf(fmaxf(v[j].x, v[j].y), fmaxf(v[j].z, v[j].w)));
  }
#pragma unroll
  for (int o = 32; o; o >>= 1) m = fmaxf(m, __shfl_xor(m, o));
  if (lane == 0) red[wave] = m;
  __syncthreads();
  if (tid == 0) bc = fmaxf(fmaxf(red[0], red[1]), fmaxf(red[2], red[3]));
  __syncthreads();
  m = bc;
  float s = 0.f;
#pragma unroll
  for (int j = 0; j < 4; j++) {
    v[j].x = __expf(v[j].x - m);
    v[j].y = __expf(v[j].y - m);
    v[j].z = __expf(v[j].z - m);
    v[j].w = __expf(v[j].w - m);
    s += v[j].x + v[j].y + v[j].z + v[j].w;
  }
#pragma unroll
  for (int o = 32; o; o >>= 1) s += __shfl_xor(s, o);
  __syncthreads();
  if (lane == 0) red[wave] = s;
  __syncthreads();
  if (tid == 0) bc = red[0] + red[1] + red[2] + red[3];
  __syncthreads();
  float r = 1.0f / bc;
  f16x4* Pr = (f16x4*)(P + (size_t)row * SEQ);
#pragma unroll
  for (int j = 0; j < 4; j++) {
    f16x4 o = {(half_t)(v[j].x * r), (half_t)(v[j].y * r), (half_t)(v[j].z * r),
               (half_t)(v[j].w * r)};
    Pr[tid + j * 256] = o;
  }
}

// ---------------- naive fp32 fallback (no workspace needed) ----------------
__global__ __launch_bounds__(256) void naive_attn(const float* __restrict__ enc,
                                                  const float* __restrict__ dec,
                                                  float* __restrict__ out) {
  const int b = blockIdx.y, t = blockIdx.x;
  const float* encb = enc + (size_t)b * SEQ * DDIM;
  const float* q = dec + ((size_t)b * SEQ + t) * DDIM;
  __shared__ float qs[DDIM];
  __shared__ float sc[SEQ];
  __shared__ float red[4];
  __shared__ float bc;
  const int tid = threadIdx.x, lane = tid & 63, wave = tid >> 6;
  for (int i = tid; i < DDIM; i += 256) qs[i] = q[i];
  __syncthreads();
  for (int e = tid; e < SEQ; e += 256) {
    const float* er = encb + (size_t)e * DDIM;
    float s = 0.f;
    for (int d = 0; d < DDIM; d += 4) {
      float4 ev = *(const float4*)(er + d);
      s += ev.x * qs[d] + ev.y * qs[d + 1] + ev.z * qs[d + 2] + ev.w * qs[d + 3];
    }
    sc[e] = s;
  }
  __syncthreads();
  float m = -1e30f;
  for (int e = tid; e < SEQ; e += 256) m = fmaxf(m, sc[e]);
#pragma unroll
  for (int o = 32; o; o >>= 1) m = fmaxf(m, __shfl_xor(m, o));
  if (lane == 0) red[wave] = m;
  __syncthreads();
  if (tid == 0) bc = fmaxf(fmaxf(red[0], red[1]), fmaxf(red[2], red[3]));
  __syncthreads();
  m = bc;
  float s = 0.f;
  for (int e = tid; e < SEQ; e += 256) {
    float p = __expf(sc[e] - m);
    sc[e] = p;
    s += p;
  }
#pragma unroll
  for (int o = 32; o; o >>= 1) s += __shfl_xor(s, o);
  __syncthreads();
  if (lane == 0) red[wave] = s;
  __syncthreads();
  if (tid == 0) bc = red[0] + red[1] + red[2] + red[3];
  __syncthreads();
  const float rinv = 1.0f / bc;
  const int d0 = tid * 4;
  float4 acc = {0.f, 0.f, 0.f, 0.f};
  for (int e = 0; e < SEQ; e++) {
    float p = sc[e];
    float4 ev = *(const float4*)(encb + (size_t)e * DDIM + d0);
    acc.x += p * ev.x;
    acc.y += p * ev.y;
    acc.z += p * ev.z;
    acc.w += p * ev.w;
  }
  float4* o4 = (float4*)(out + ((size_t)b * SEQ + t) * DDIM + d0);
  float4 res = {acc.x * rinv, acc.y * rinv, acc.z * rinv, acc.w * rinv};
  *o4 = res;
}

extern "C" void kernel_launch(void* const* d_in, const int* in_sizes, int n_in, void* d_out,
                              int out_size, void* d_ws, size_t ws_size, hipStream_t stream) {
  const float* enc = (const float*)d_in[0];
  const float* dec = (const float*)d_in[1];
  float* out = (float*)d_out;

  const size_t SZ_S = (size_t)SEQ * SEQ * 4;            // 64 MiB
  const size_t SZ_P = (size_t)SEQ * SEQ * 2;            // 32 MiB (one batch)
  const size_t SZ_PALL = (size_t)NBATCH * SEQ * SEQ * 2;  // 128 MiB (all batches)
  const size_t SZ_H = (size_t)NBATCH * SEQ * DDIM * 2;  // 32 MiB each
  const size_t NEED_SPLITK = SZ_S + SZ_P + 3 * SZ_H;    // 192 MiB (proven available R1)
  const size_t NEED_BATCH = SZ_S + SZ_PALL + 3 * SZ_H;  // 288 MiB (preferred if present)

  const int nconv = NBATCH * SEQ * DDIM / 4 / 256;  // 16384 blocks

  if (ws_size >= NEED_BATCH) {
    // ---- batched-GEMM2 path: keep P for all batches, one grid-z=4 launch ----
    char* w = (char*)d_ws;
    float* S = (float*)w;                                  // reused per batch
    half_t* Pall = (half_t*)(w + SZ_S);
    half_t* decF = (half_t*)(w + SZ_S + SZ_PALL);
    half_t* encF = (half_t*)(w + SZ_S + SZ_PALL + SZ_H);
    half_t* encT = (half_t*)(w + SZ_S + SZ_PALL + 2 * SZ_H);

    conv_f16<<<nconv, 256, 0, stream>>>(dec, decF);
    conv_f16<<<nconv, 256, 0, stream>>>(enc, encF);
    transpose_f16<<<dim3(SEQ / 32, DDIM / 32, NBATCH), 256, 0, stream>>>(enc, encT);

    for (int b = 0; b < NBATCH; b++) {
      const size_t eo = (size_t)b * SEQ * DDIM;
      gemm_f16<<<dim3(SEQ / BM, SEQ / BN, 1), 256, 0, stream>>>(decF + eo, encF + eo, S, SEQ,
                                                                SEQ, DDIM, DDIM, 0, 0, 0, 0);
      softmax_rows<<<SEQ, 256, 0, stream>>>(S, Pall + (size_t)b * SEQ * SEQ);
    }
    // out[b][t][d] = sum_e P[b][t][e] * encT[b][d][e]; 1024 blocks = 4/CU
    gemm_f16<<<dim3(SEQ / BM, DDIM / BN, NBATCH), 256, 0, stream>>>(
        Pall, encT, out, SEQ, DDIM, SEQ, SEQ, (long)SEQ * SEQ, (long)DDIM * SEQ,
        (long)SEQ * DDIM, 0);
  } else if (ws_size >= NEED_SPLITK) {
    // ---- split-K path: grid-z = 4 K-chunks, atomic-add fp32 epilogue ----
    char* w = (char*)d_ws;
    float* S = (float*)w;
    half_t* P = (half_t*)(w + SZ_S);
    half_t* decF = (half_t*)(w + SZ_S + SZ_P);
    half_t* encF = (half_t*)(w + SZ_S + SZ_P + SZ_H);
    half_t* encT = (half_t*)(w + SZ_S + SZ_P + 2 * SZ_H);

    hipMemsetAsync(out, 0, (size_t)NBATCH * SEQ * DDIM * 4, stream);
    conv_f16<<<nconv, 256, 0, stream>>>(dec, decF);
    conv_f16<<<nconv, 256, 0, stream>>>(enc, encF);
    transpose_f16<<<dim3(SEQ / 32, DDIM / 32, NBATCH), 256, 0, stream>>>(enc, encT);

    for (int b = 0; b < NBATCH; b++) {
      const size_t eo = (size_t)b * SEQ * DDIM;
      // S[t][e] = dec[t]·enc[e]
      gemm_f16<<<dim3(SEQ / BM, SEQ / BN, 1), 256, 0, stream>>>(decF + eo, encF + eo, S, SEQ,
                                                                SEQ, DDIM, DDIM, 0, 0, 0, 0);
      softmax_rows<<<SEQ, 256, 0, stream>>>(S, P);
      // out[t][d] += sum_{e in chunk z} P[t][e] * encT[d][e]; 1024 blocks = 4/CU
      gemm_f16<<<dim3(SEQ / BM, DDIM / BN, 4), 256, 0, stream>>>(
          P, encT + (size_t)b * DDIM * SEQ, out + eo, SEQ, DDIM, SEQ, SEQ / 4, SEQ / 4,
          SEQ / 4, 0, 1);
    }
  } else {
    naive_attn<<<dim3(SEQ, NBATCH), 256, 0, stream>>>(enc, dec, out);
  }
}

// Round 2
// 749.112 us; speedup vs baseline: 1.0991x; 1.0991x over previous
//
#include <hip/hip_runtime.h>
#include <hip/hip_fp16.h>

typedef _Float16 half_t;
typedef _Float16 f16x8 __attribute__((ext_vector_type(8)));
typedef _Float16 f16x4 __attribute__((ext_vector_type(4)));
typedef float f32x4 __attribute__((ext_vector_type(4)));

#define SEQ 4096
#define DDIM 1024
#define NBATCH 4

// async global->LDS, 16B per lane. LDS dest is wave-uniform base + lane*16,
// so the per-lane lds pointer MUST be base + lane*16 in wave-lane order.
__device__ __forceinline__ void gload16(const half_t* g, half_t* l) {
  __builtin_amdgcn_global_load_lds((const __attribute__((address_space(1))) void*)g,
                                   (__attribute__((address_space(3))) void*)l, 16, 0, 0);
}

// ---------------- fp32 -> fp16 elementwise convert ----------------
__global__ __launch_bounds__(256) void conv_f16(const float* __restrict__ src,
                                                half_t* __restrict__ dst) {
  int i = blockIdx.x * 256 + threadIdx.x;
  float4 x = ((const float4*)src)[i];
  f16x4 o = {(half_t)x.x, (half_t)x.y, (half_t)x.z, (half_t)x.w};
  *(f16x4*)(dst + (size_t)i * 4) = o;
}

// ------- enc [b][e][d] fp32 -> encF [b][e][d] f16 AND encT [b][d][e] f16 ----
// Fused: one read of enc feeds both outputs (saves a full 64 MiB pass).
__global__ __launch_bounds__(256) void transconv_f16(const float* __restrict__ src,
                                                     half_t* __restrict__ dstF,
                                                     half_t* __restrict__ dstT) {
  __shared__ float tile[32][33];
  int b = blockIdx.z;
  int e0 = blockIdx.x * 32, d0 = blockIdx.y * 32;
  const float* s = src + (size_t)b * SEQ * DDIM;
  half_t* df = dstF + (size_t)b * SEQ * DDIM;
  half_t* dt = dstT + (size_t)b * DDIM * SEQ;
  int tx = threadIdx.x & 31, ty = threadIdx.x >> 5;
#pragma unroll
  for (int i = 0; i < 4; i++) {
    int e = e0 + ty + i * 8;
    float v = s[(size_t)e * DDIM + d0 + tx];
    tile[ty + i * 8][tx] = v;
    df[(size_t)e * DDIM + d0 + tx] = (half_t)v;
  }
  __syncthreads();
#pragma unroll
  for (int i = 0; i < 4; i++) {
    int d = d0 + ty + i * 8;
    dt[(size_t)d * SEQ + e0 + tx] = (half_t)tile[tx][ty + i * 8];
  }
}

// ---------------- fp16 BT GEMM: C[M][N] fp32 = A[M][K] * B[N][K]^T ----------
// 128x128 tile, BK=64, global_load_lds width-16 staging, XOR chunk swizzle
// (slot = chunk ^ (row&7)) for conflict-free ds_read_b128 fragments.
// NEW (R2): 2-phase double-buffered pipeline (T3 minimum recipe, m228d):
//   STAGE(next buf) issued BEFORE compute(cur buf); ONE __syncthreads per
//   K-step (its vmcnt(0)+lgkmcnt(0) drain provides all ordering). Next-tile
//   HBM latency hides under current-tile MFMA instead of being exposed by a
//   per-step vmcnt(0) drain (round-1 counters: 3600 cyc/K-step vs 614 cyc
//   of MFMA work -> latency-bound, MfmaUtil 13%).
// blockIdx.z selects batch (sA/sB/sC elem strides) OR split-K chunk
// (sA=sB=kc, sC=0, atom=1 -> fp32 atomic-add epilogue).
#define BM 128
#define BN 128
#define BK 64

__global__ __launch_bounds__(256) void gemm_f16(const half_t* __restrict__ A,
                                                const half_t* __restrict__ B,
                                                float* __restrict__ C, int M, int N, int K,
                                                int kc, long sA, long sB, long sC, int atom) {
  A += (size_t)blockIdx.z * (size_t)sA;
  B += (size_t)blockIdx.z * (size_t)sB;
  C += (size_t)blockIdx.z * (size_t)sC;
  __shared__ __align__(16) half_t As[2][BM * BK];
  __shared__ __align__(16) half_t Bs[2][BN * BK];
  const int tid = threadIdx.x;
  const int bm = blockIdx.x, bn = blockIdx.y;
  const int wave = tid >> 6, lane = tid & 63;
  const int wm = (wave & 1) * 64, wn = (wave >> 1) * 64;
  const int mrow = lane & 15, quad = lane >> 4;

  f32x4 acc[4][4];
#pragma unroll
  for (int i = 0; i < 4; i++)
#pragma unroll
    for (int j = 0; j < 4; j++) acc[i][j] = {0.f, 0.f, 0.f, 0.f};

  const half_t* Ag = A + (size_t)(bm * BM) * K;
  const half_t* Bg = B + (size_t)(bn * BN) * K;

  // staging geometry: tile = 128 rows x 8 chunks(16B); cid = i*256 + tid
  // row = cid>>3, slot = cid&7, global chunk = slot ^ (row&7).
  // LDS dest addr = base + cid*16B -> lane-contiguous (global_load_lds req).
  auto stage = [&](int buf, int k0) {
#pragma unroll
    for (int i = 0; i < 4; i++) {
      int cid = i * 256 + tid;
      int row = cid >> 3, slot = cid & 7;
      int chunk = slot ^ (row & 7);
      gload16(Ag + (size_t)row * K + k0 + chunk * 8, &As[buf][row * BK + slot * 8]);
      gload16(Bg + (size_t)row * K + k0 + chunk * 8, &Bs[buf][row * BK + slot * 8]);
    }
  };

  stage(0, 0);
  __syncthreads();  // drains vmcnt(0); buf0 ready for everyone
  int cur = 0;
  for (int k0 = 0; k0 < kc; k0 += BK) {
    if (k0 + BK < kc) stage(cur ^ 1, k0 + BK);  // issue next tile's loads
    // compute current tile (data guaranteed by barrier at end of prev iter)
#pragma unroll
    for (int ks = 0; ks < 2; ks++) {
      f16x8 af[4], bf[4];
#pragma unroll
      for (int i = 0; i < 4; i++) {
        int ra = wm + i * 16 + mrow;
        int rb = wn + i * 16 + mrow;
        int sa = (ks * 4 + quad) ^ (ra & 7);
        int sb = (ks * 4 + quad) ^ (rb & 7);
        af[i] = *(const f16x8*)(&As[cur][ra * BK + sa * 8]);
        bf[i] = *(const f16x8*)(&Bs[cur][rb * BK + sb * 8]);
      }
#pragma unroll
      for (int mi = 0; mi < 4; mi++)
#pragma unroll
        for (int ni = 0; ni < 4; ni++)
          acc[mi][ni] =
              __builtin_amdgcn_mfma_f32_16x16x32_f16(af[mi], bf[ni], acc[mi][ni], 0, 0, 0);
    }
    // ONE barrier per K-step: __syncthreads emits s_waitcnt vmcnt(0)
    // lgkmcnt(0) + s_barrier -> my next-tile loads landed, my ds_reads done,
    // and after the barrier everyone's have too.
    __syncthreads();
    cur ^= 1;
  }
  // epilogue: D[row=(quad*4+r)][col=lane&15] per 16x16 tile [measured m89/m91]
#pragma unroll
  for (int mi = 0; mi < 4; mi++) {
#pragma unroll
    for (int ni = 0; ni < 4; ni++) {
      int row0 = bm * BM + wm + mi * 16 + quad * 4;
      int col = bn * BN + wn + ni * 16 + mrow;
      float* Cp = C + (size_t)row0 * N + col;
      if (atom) {
#pragma unroll
        for (int r = 0; r < 4; r++) unsafeAtomicAdd(Cp + (size_t)r * N, acc[mi][ni][r]);
      } else {
#pragma unroll
        for (int r = 0; r < 4; r++) Cp[(size_t)r * N] = acc[mi][ni][r];
      }
    }
  }
}

// ---------------- row softmax: S[row][:] fp32 -> P[row][:] fp16 ----------------
__global__ __launch_bounds__(256) void softmax_rows(const float* __restrict__ S,
                                                    half_t* __restrict__ P) {
  const int row = blockIdx.x;
  const float4* Sr = (const float4*)(S + (size_t)row * SEQ);
  const int tid = threadIdx.x, lane = tid & 63, wave = tid >> 6;
  __shared__ float red[4];
  __shared__ float bc;
  float4 v[4];
  float m = -1e30f;
#pragma unroll
  for (int j = 0; j < 4; j++) {
    v[j] = Sr[tid + j * 256];
    m = fmaxf(m, fmaxf(fmaxf(v[j].x, v[j].y), fmaxf(v[j].z, v[j].w)));
  }
#pragma unroll
  for (int o = 32; o; o >>= 1) m = fmaxf(m, __shfl_xor(m, o));
  if (lane == 0) red[wave] = m;
  __syncthreads();
  if (tid == 0) bc = fmaxf(fmaxf(red[0], red[1]), fmaxf(red[2], red[3]));
  __syncthreads();
  m = bc;
  float s = 0.f;
#pragma unroll
  for (int j = 0; j < 4; j++) {
    v[j].x = __expf(v[j].x - m);
    v[j].y = __expf(v[j].y - m);
    v[j].z = __expf(v[j].z - m);
    v[j].w = __expf(v[j].w - m);
    s += v[j].x + v[j].y + v[j].z + v[j].w;
  }
#pragma unroll
  for (int o = 32; o; o >>= 1) s += __shfl_xor(s, o);
  __syncthreads();
  if (lane == 0) red[wave] = s;
  __syncthreads();
  if (tid == 0) bc = red[0] + red[1] + red[2] + red[3];
  __syncthreads();
  float r = 1.0f / bc;
  f16x4* Pr = (f16x4*)(P + (size_t)row * SEQ);
#pragma unroll
  for (int j = 0; j < 4; j++) {
    f16x4 o = {(half_t)(v[j].x * r), (half_t)(v[j].y * r), (half_t)(v[j].z * r),
               (half_t)(v[j].w * r)};
    Pr[tid + j * 256] = o;
  }
}

// ---------------- naive fp32 fallback (no workspace needed) ----------------
__global__ __launch_bounds__(256) void naive_attn(const float* __restrict__ enc,
                                                  const float* __restrict__ dec,
                                                  float* __restrict__ out) {
  const int b = blockIdx.y, t = blockIdx.x;
  const float* encb = enc + (size_t)b * SEQ * DDIM;
  const float* q = dec + ((size_t)b * SEQ + t) * DDIM;
  __shared__ float qs[DDIM];
  __shared__ float sc[SEQ];
  __shared__ float red[4];
  __shared__ float bc;
  const int tid = threadIdx.x, lane = tid & 63, wave = tid >> 6;
  for (int i = tid; i < DDIM; i += 256) qs[i] = q[i];
  __syncthreads();
  for (int e = tid; e < SEQ; e += 256) {
    const float* er = encb + (size_t)e * DDIM;
    float s = 0.f;
    for (int d = 0; d < DDIM; d += 4) {
      float4 ev = *(const float4*)(er + d);
      s += ev.x * qs[d] + ev.y * qs[d + 1] + ev.z * qs[d + 2] + ev.w * qs[d + 3];
    }
    sc[e] = s;
  }
  __syncthreads();
  float m = -1e30f;
  for (int e = tid; e < SEQ; e += 256) m = fmaxf(m, sc[e]);
#pragma unroll
  for (int o = 32; o; o >>= 1) m = fmaxf(m, __shfl_xor(m, o));
  if (lane == 0) red[wave] = m;
  __syncthreads();
  if (tid == 0) bc = fmaxf(fmaxf(red[0], red[1]), fmaxf(red[2], red[3]));
  __syncthreads();
  m = bc;
  float s = 0.f;
  for (int e = tid; e < SEQ; e += 256) {
    float p = __expf(sc[e] - m);
    sc[e] = p;
    s += p;
  }
#pragma unroll
  for (int o = 32; o; o >>= 1) s += __shfl_xor(s, o);
  __syncthreads();
  if (lane == 0) red[wave] = s;
  __syncthreads();
  if (tid == 0) bc = red[0] + red[1] + red[2] + red[3];
  __syncthreads();
  const float rinv = 1.0f / bc;
  const int d0 = tid * 4;
  float4 acc = {0.f, 0.f, 0.f, 0.f};
  for (int e = 0; e < SEQ; e++) {
    float p = sc[e];
    float4 ev = *(const float4*)(encb + (size_t)e * DDIM + d0);
    acc.x += p * ev.x;
    acc.y += p * ev.y;
    acc.z += p * ev.z;
    acc.w += p * ev.w;
  }
  float4* o4 = (float4*)(out + ((size_t)b * SEQ + t) * DDIM + d0);
  float4 res = {acc.x * rinv, acc.y * rinv, acc.z * rinv, acc.w * rinv};
  *o4 = res;
}

extern "C" void kernel_launch(void* const* d_in, const int* in_sizes, int n_in, void* d_out,
                              int out_size, void* d_ws, size_t ws_size, hipStream_t stream) {
  const float* enc = (const float*)d_in[0];
  const float* dec = (const float*)d_in[1];
  float* out = (float*)d_out;

  const size_t SZ_S = (size_t)SEQ * SEQ * 4;              // 64 MiB (one batch)
  const size_t SZ_SALL = (size_t)NBATCH * SEQ * SEQ * 4;  // 256 MiB
  const size_t SZ_P = (size_t)SEQ * SEQ * 2;              // 32 MiB (one batch)
  const size_t SZ_PALL = (size_t)NBATCH * SEQ * SEQ * 2;  // 128 MiB
  const size_t SZ_H = (size_t)NBATCH * SEQ * DDIM * 2;    // 32 MiB each
  const size_t NEED_FULL = SZ_SALL + SZ_PALL + 3 * SZ_H;  // 480 MiB (opportunistic)
  const size_t NEED_BATCH = SZ_S + SZ_PALL + 3 * SZ_H;    // 288 MiB (proven R1)
  const size_t NEED_SPLITK = SZ_S + SZ_P + 3 * SZ_H;      // 192 MiB (proven R0)

  const int nconv = NBATCH * SEQ * DDIM / 4 / 256;  // 16384 blocks per tensor

  if (ws_size >= NEED_FULL) {
    // ---- fully-batched path: 5 dispatches, deep grids, no per-batch churn ----
    char* w = (char*)d_ws;
    float* Sall = (float*)w;
    half_t* Pall = (half_t*)(w + SZ_SALL);
    half_t* decF = (half_t*)(w + SZ_SALL + SZ_PALL);
    half_t* encF = (half_t*)(w + SZ_SALL + SZ_PALL + SZ_H);
    half_t* encT = (half_t*)(w + SZ_SALL + SZ_PALL + 2 * SZ_H);

    conv_f16<<<nconv, 256, 0, stream>>>(dec, decF);
    transconv_f16<<<dim3(SEQ / 32, DDIM / 32, NBATCH), 256, 0, stream>>>(enc, encF, encT);
    // S[b][t][e] = dec[b][t]·enc[b][e]; 4096 blocks = 16/CU queue
    gemm_f16<<<dim3(SEQ / BM, SEQ / BN, NBATCH), 256, 0, stream>>>(
        decF, encF, Sall, SEQ, SEQ, DDIM, DDIM, (long)SEQ * DDIM, (long)SEQ * DDIM,
        (long)SEQ * SEQ, 0);
    softmax_rows<<<NBATCH * SEQ, 256, 0, stream>>>(Sall, Pall);
    // out[b][t][d] = sum_e P[b][t][e] * encT[b][d][e]
    gemm_f16<<<dim3(SEQ / BM, DDIM / BN, NBATCH), 256, 0, stream>>>(
        Pall, encT, out, SEQ, DDIM, SEQ, SEQ, (long)SEQ * SEQ, (long)DDIM * SEQ,
        (long)SEQ * DDIM, 0);
  } else if (ws_size >= NEED_BATCH) {
    // ---- per-batch GEMM1/softmax, batched GEMM2 (round-1 structure) ----
    char* w = (char*)d_ws;
    float* S = (float*)w;  // reused per batch
    half_t* Pall = (half_t*)(w + SZ_S);
    half_t* decF = (half_t*)(w + SZ_S + SZ_PALL);
    half_t* encF = (half_t*)(w + SZ_S + SZ_PALL + SZ_H);
    half_t* encT = (half_t*)(w + SZ_S + SZ_PALL + 2 * SZ_H);

    conv_f16<<<nconv, 256, 0, stream>>>(dec, decF);
    transconv_f16<<<dim3(SEQ / 32, DDIM / 32, NBATCH), 256, 0, stream>>>(enc, encF, encT);

    for (int b = 0; b < NBATCH; b++) {
      const size_t eo = (size_t)b * SEQ * DDIM;
      gemm_f16<<<dim3(SEQ / BM, SEQ / BN, 1), 256, 0, stream>>>(decF + eo, encF + eo, S, SEQ,
                                                                SEQ, DDIM, DDIM, 0, 0, 0, 0);
      softmax_rows<<<SEQ, 256, 0, stream>>>(S, Pall + (size_t)b * SEQ * SEQ);
    }
    gemm_f16<<<dim3(SEQ / BM, DDIM / BN, NBATCH), 256, 0, stream>>>(
        Pall, encT, out, SEQ, DDIM, SEQ, SEQ, (long)SEQ * SEQ, (long)DDIM * SEQ,
        (long)SEQ * DDIM, 0);
  } else if (ws_size >= NEED_SPLITK) {
    // ---- split-K path: grid-z = 4 K-chunks, atomic-add fp32 epilogue ----
    char* w = (char*)d_ws;
    float* S = (float*)w;
    half_t* P = (half_t*)(w + SZ_S);
    half_t* decF = (half_t*)(w + SZ_S + SZ_P);
    half_t* encF = (half_t*)(w + SZ_S + SZ_P + SZ_H);
    half_t* encT = (half_t*)(w + SZ_S + SZ_P + 2 * SZ_H);

    hipMemsetAsync(out, 0, (size_t)NBATCH * SEQ * DDIM * 4, stream);
    conv_f16<<<nconv, 256, 0, stream>>>(dec, decF);
    transconv_f16<<<dim3(SEQ / 32, DDIM / 32, NBATCH), 256, 0, stream>>>(enc, encF, encT);

    for (int b = 0; b < NBATCH; b++) {
      const size_t eo = (size_t)b * SEQ * DDIM;
      gemm_f16<<<dim3(SEQ / BM, SEQ / BN, 1), 256, 0, stream>>>(decF + eo, encF + eo, S, SEQ,
                                                                SEQ, DDIM, DDIM, 0, 0, 0, 0);
      softmax_rows<<<SEQ, 256, 0, stream>>>(S, P);
      gemm_f16<<<dim3(SEQ / BM, DDIM / BN, 4), 256, 0, stream>>>(
          P, encT + (size_t)b * DDIM * SEQ, out + eo, SEQ, DDIM, SEQ, SEQ / 4, SEQ / 4,
          SEQ / 4, 0, 1);
    }
  } else {
    naive_attn<<<dim3(SEQ, NBATCH), 256, 0, stream>>>(enc, dec, out);
  }
}

// Round 3
// 742.037 us; speedup vs baseline: 1.1095x; 1.0095x over previous
//
#include <hip/hip_runtime.h>
#include <hip/hip_fp16.h>

typedef _Float16 half_t;
typedef _Float16 f16x8 __attribute__((ext_vector_type(8)));
typedef _Float16 f16x4 __attribute__((ext_vector_type(4)));
typedef float f32x4 __attribute__((ext_vector_type(4)));

#define SEQ 4096
#define DDIM 1024
#define NBATCH 4

// async global->LDS, 16B per lane. LDS dest is wave-uniform base + lane*16,
// so the per-lane lds pointer MUST be base + lane*16 in wave-lane order.
__device__ __forceinline__ void gload16(const half_t* g, half_t* l) {
  __builtin_amdgcn_global_load_lds((const __attribute__((address_space(1))) void*)g,
                                   (__attribute__((address_space(3))) void*)l, 16, 0, 0);
}

// ---------------- fp32 -> fp16 elementwise convert ----------------
__global__ __launch_bounds__(256) void conv_f16(const float* __restrict__ src,
                                                half_t* __restrict__ dst) {
  int i = blockIdx.x * 256 + threadIdx.x;
  float4 x = ((const float4*)src)[i];
  f16x4 o = {(half_t)x.x, (half_t)x.y, (half_t)x.z, (half_t)x.w};
  *(f16x4*)(dst + (size_t)i * 4) = o;
}

// ------- enc [b][e][d] fp32 -> encF [b][e][d] f16 AND encT [b][d][e] f16 ----
// Fused: one read of enc feeds both outputs (saves a full 64 MiB pass).
__global__ __launch_bounds__(256) void transconv_f16(const float* __restrict__ src,
                                                     half_t* __restrict__ dstF,
                                                     half_t* __restrict__ dstT) {
  __shared__ float tile[32][33];
  int b = blockIdx.z;
  int e0 = blockIdx.x * 32, d0 = blockIdx.y * 32;
  const float* s = src + (size_t)b * SEQ * DDIM;
  half_t* df = dstF + (size_t)b * SEQ * DDIM;
  half_t* dt = dstT + (size_t)b * DDIM * SEQ;
  int tx = threadIdx.x & 31, ty = threadIdx.x >> 5;
#pragma unroll
  for (int i = 0; i < 4; i++) {
    int e = e0 + ty + i * 8;
    float v = s[(size_t)e * DDIM + d0 + tx];
    tile[ty + i * 8][tx] = v;
    df[(size_t)e * DDIM + d0 + tx] = (half_t)v;
  }
  __syncthreads();
#pragma unroll
  for (int i = 0; i < 4; i++) {
    int d = d0 + ty + i * 8;
    dt[(size_t)d * SEQ + e0 + tx] = (half_t)tile[tx][ty + i * 8];
  }
}

// ------------- fp16 BT GEMM, 256x256 tile: C[M][N] = A[M][K] * B[N][K]^T ----
// R3: 2x arithmetic intensity vs the 128^2 tile. Evidence: every 2-barrier
// schedule sustains ~9-10 B/cyc/CU ingest (round-1/2 GEMM1 = 3400 cyc per
// 32KiB K-step; guide m230); at fixed ingest, doubling FLOP/byte doubles
// TF. 256^2+2ph measured 682 TF refcheck'd (m230) vs our 380 at 128^2.
// 512 thr = 8 waves (2Mx4N), per-wave 128x64 output (8x4 16x16 frags).
// LDS 128 KiB (dbuf) -> 1 block/CU; grid 256 blocks = exactly 1/CU, no
// tail, no reliance on co-residency. Per-K-step compute (~2400 cyc of
// MFMA+ds_read) now covers load latency inside the single-barrier loop.
// XOR chunk swizzle (slot = chunk ^ (row&7)) kept: bank conflicts = 0.
// blockIdx.z: batch (sA/sB/sC elem strides) OR split-K chunk
// (sA=sB=kc, sC=0, atom=1 -> fp32 atomic-add epilogue).
#define TM 256
#define TN 256
#define TK 64

__global__ __launch_bounds__(512, 2) void gemm256_f16(const half_t* __restrict__ A,
                                                      const half_t* __restrict__ B,
                                                      float* __restrict__ C, int M, int N,
                                                      int K, int kc, long sA, long sB, long sC,
                                                      int atom) {
  A += (size_t)blockIdx.z * (size_t)sA;
  B += (size_t)blockIdx.z * (size_t)sB;
  C += (size_t)blockIdx.z * (size_t)sC;
  __shared__ __align__(16) half_t As[2][TM * TK];
  __shared__ __align__(16) half_t Bs[2][TN * TK];
  const int tid = threadIdx.x;
  const int wave = tid >> 6, lane = tid & 63;
  const int wm = (wave >> 2) * 128, wn = (wave & 3) * 64;  // 2x4 wave grid
  const int mrow = lane & 15, quad = lane >> 4;

  f32x4 acc[8][4];
#pragma unroll
  for (int i = 0; i < 8; i++)
#pragma unroll
    for (int j = 0; j < 4; j++) acc[i][j] = {0.f, 0.f, 0.f, 0.f};

  const half_t* Ag = A + (size_t)(blockIdx.x * TM) * K;
  const half_t* Bg = B + (size_t)(blockIdx.y * TN) * K;

  // staging: tile = 256 rows x 8 chunks(16B) = 32KiB each of A,B per K-step.
  // cid = i*512 + tid; row = cid>>3, slot = cid&7, global chunk = slot^(row&7).
  // LDS dest = base + cid*16B: lane-contiguous (global_load_lds requirement).
  auto stage = [&](int buf, int k0) {
#pragma unroll
    for (int i = 0; i < 4; i++) {
      int cid = i * 512 + tid;
      int row = cid >> 3, slot = cid & 7;
      int chunk = slot ^ (row & 7);
      gload16(Ag + (size_t)row * K + k0 + chunk * 8, &As[buf][row * TK + slot * 8]);
      gload16(Bg + (size_t)row * K + k0 + chunk * 8, &Bs[buf][row * TK + slot * 8]);
    }
  };

  stage(0, 0);
  __syncthreads();  // drains vmcnt(0): buf0 ready for everyone
  int cur = 0;
  for (int k0 = 0; k0 < kc; k0 += TK) {
    if (k0 + TK < kc) stage(cur ^ 1, k0 + TK);  // issue next tile first (T3)
#pragma unroll
    for (int ks = 0; ks < 2; ks++) {
      f16x8 af[8], bf[4];
#pragma unroll
      for (int i = 0; i < 8; i++) {
        int ra = wm + i * 16 + mrow;
        int sa = (ks * 4 + quad) ^ (ra & 7);
        af[i] = *(const f16x8*)(&As[cur][ra * TK + sa * 8]);
      }
#pragma unroll
      for (int j = 0; j < 4; j++) {
        int rb = wn + j * 16 + mrow;
        int sb = (ks * 4 + quad) ^ (rb & 7);
        bf[j] = *(const f16x8*)(&Bs[cur][rb * TK + sb * 8]);
      }
#pragma unroll
      for (int mi = 0; mi < 8; mi++)
#pragma unroll
        for (int ni = 0; ni < 4; ni++)
          acc[mi][ni] =
              __builtin_amdgcn_mfma_f32_16x16x32_f16(af[mi], bf[ni], acc[mi][ni], 0, 0, 0);
    }
    // ONE barrier per K-step: __syncthreads' vmcnt(0)+lgkmcnt(0) drain
    // orders my next-tile loads and my ds_reads for the whole block.
    __syncthreads();
    cur ^= 1;
  }
  // epilogue: D[row=(quad*4+r)][col=lane&15] per 16x16 tile [m89/m91]
#pragma unroll
  for (int mi = 0; mi < 8; mi++) {
#pragma unroll
    for (int ni = 0; ni < 4; ni++) {
      int row0 = blockIdx.x * TM + wm + mi * 16 + quad * 4;
      int col = blockIdx.y * TN + wn + ni * 16 + mrow;
      float* Cp = C + (size_t)row0 * N + col;
      if (atom) {
#pragma unroll
        for (int r = 0; r < 4; r++) unsafeAtomicAdd(Cp + (size_t)r * N, acc[mi][ni][r]);
      } else {
#pragma unroll
        for (int r = 0; r < 4; r++) Cp[(size_t)r * N] = acc[mi][ni][r];
      }
    }
  }
}

// ---------------- row softmax: S[row][:] fp32 -> P[row][:] fp16 ----------------
__global__ __launch_bounds__(256) void softmax_rows(const float* __restrict__ S,
                                                    half_t* __restrict__ P) {
  const int row = blockIdx.x;
  const float4* Sr = (const float4*)(S + (size_t)row * SEQ);
  const int tid = threadIdx.x, lane = tid & 63, wave = tid >> 6;
  __shared__ float red[4];
  __shared__ float bc;
  float4 v[4];
  float m = -1e30f;
#pragma unroll
  for (int j = 0; j < 4; j++) {
    v[j] = Sr[tid + j * 256];
    m = fmaxf(m, fmaxf(fmaxf(v[j].x, v[j].y), fmaxf(v[j].z, v[j].w)));
  }
#pragma unroll
  for (int o = 32; o; o >>= 1) m = fmaxf(m, __shfl_xor(m, o));
  if (lane == 0) red[wave] = m;
  __syncthreads();
  if (tid == 0) bc = fmaxf(fmaxf(red[0], red[1]), fmaxf(red[2], red[3]));
  __syncthreads();
  m = bc;
  float s = 0.f;
#pragma unroll
  for (int j = 0; j < 4; j++) {
    v[j].x = __expf(v[j].x - m);
    v[j].y = __expf(v[j].y - m);
    v[j].z = __expf(v[j].z - m);
    v[j].w = __expf(v[j].w - m);
    s += v[j].x + v[j].y + v[j].z + v[j].w;
  }
#pragma unroll
  for (int o = 32; o; o >>= 1) s += __shfl_xor(s, o);
  __syncthreads();
  if (lane == 0) red[wave] = s;
  __syncthreads();
  if (tid == 0) bc = red[0] + red[1] + red[2] + red[3];
  __syncthreads();
  float r = 1.0f / bc;
  f16x4* Pr = (f16x4*)(P + (size_t)row * SEQ);
#pragma unroll
  for (int j = 0; j < 4; j++) {
    f16x4 o = {(half_t)(v[j].x * r), (half_t)(v[j].y * r), (half_t)(v[j].z * r),
               (half_t)(v[j].w * r)};
    Pr[tid + j * 256] = o;
  }
}

// ---------------- naive fp32 fallback (no workspace needed) ----------------
__global__ __launch_bounds__(256) void naive_attn(const float* __restrict__ enc,
                                                  const float* __restrict__ dec,
                                                  float* __restrict__ out) {
  const int b = blockIdx.y, t = blockIdx.x;
  const float* encb = enc + (size_t)b * SEQ * DDIM;
  const float* q = dec + ((size_t)b * SEQ + t) * DDIM;
  __shared__ float qs[DDIM];
  __shared__ float sc[SEQ];
  __shared__ float red[4];
  __shared__ float bc;
  const int tid = threadIdx.x, lane = tid & 63, wave = tid >> 6;
  for (int i = tid; i < DDIM; i += 256) qs[i] = q[i];
  __syncthreads();
  for (int e = tid; e < SEQ; e += 256) {
    const float* er = encb + (size_t)e * DDIM;
    float s = 0.f;
    for (int d = 0; d < DDIM; d += 4) {
      float4 ev = *(const float4*)(er + d);
      s += ev.x * qs[d] + ev.y * qs[d + 1] + ev.z * qs[d + 2] + ev.w * qs[d + 3];
    }
    sc[e] = s;
  }
  __syncthreads();
  float m = -1e30f;
  for (int e = tid; e < SEQ; e += 256) m = fmaxf(m, sc[e]);
#pragma unroll
  for (int o = 32; o; o >>= 1) m = fmaxf(m, __shfl_xor(m, o));
  if (lane == 0) red[wave] = m;
  __syncthreads();
  if (tid == 0) bc = fmaxf(fmaxf(red[0], red[1]), fmaxf(red[2], red[3]));
  __syncthreads();
  m = bc;
  float s = 0.f;
  for (int e = tid; e < SEQ; e += 256) {
    float p = __expf(sc[e] - m);
    sc[e] = p;
    s += p;
  }
#pragma unroll
  for (int o = 32; o; o >>= 1) s += __shfl_xor(s, o);
  __syncthreads();
  if (lane == 0) red[wave] = s;
  __syncthreads();
  if (tid == 0) bc = red[0] + red[1] + red[2] + red[3];
  __syncthreads();
  const float rinv = 1.0f / bc;
  const int d0 = tid * 4;
  float4 acc = {0.f, 0.f, 0.f, 0.f};
  for (int e = 0; e < SEQ; e++) {
    float p = sc[e];
    float4 ev = *(const float4*)(encb + (size_t)e * DDIM + d0);
    acc.x += p * ev.x;
    acc.y += p * ev.y;
    acc.z += p * ev.z;
    acc.w += p * ev.w;
  }
  float4* o4 = (float4*)(out + ((size_t)b * SEQ + t) * DDIM + d0);
  float4 res = {acc.x * rinv, acc.y * rinv, acc.z * rinv, acc.w * rinv};
  *o4 = res;
}

extern "C" void kernel_launch(void* const* d_in, const int* in_sizes, int n_in, void* d_out,
                              int out_size, void* d_ws, size_t ws_size, hipStream_t stream) {
  const float* enc = (const float*)d_in[0];
  const float* dec = (const float*)d_in[1];
  float* out = (float*)d_out;

  const size_t SZ_S = (size_t)SEQ * SEQ * 4;          // 64 MiB (one batch)
  const size_t SZ_P = (size_t)SEQ * SEQ * 2;          // 32 MiB (one batch)
  const size_t SZ_H = (size_t)NBATCH * SEQ * DDIM * 2;  // 32 MiB each
  const size_t NEED = SZ_S + SZ_P + 3 * SZ_H;         // 192 MiB (proven: this path ran R0-R2)

  const int nconv = NBATCH * SEQ * DDIM / 4 / 256;  // 16384 blocks

  if (ws_size >= NEED) {
    char* w = (char*)d_ws;
    float* S = (float*)w;
    half_t* P = (half_t*)(w + SZ_S);
    half_t* decF = (half_t*)(w + SZ_S + SZ_P);
    half_t* encF = (half_t*)(w + SZ_S + SZ_P + SZ_H);
    half_t* encT = (half_t*)(w + SZ_S + SZ_P + 2 * SZ_H);

    hipMemsetAsync(out, 0, (size_t)NBATCH * SEQ * DDIM * 4, stream);
    conv_f16<<<nconv, 256, 0, stream>>>(dec, decF);
    transconv_f16<<<dim3(SEQ / 32, DDIM / 32, NBATCH), 256, 0, stream>>>(enc, encF, encT);

    for (int b = 0; b < NBATCH; b++) {
      const size_t eo = (size_t)b * SEQ * DDIM;
      // S[t][e] = dec[t]·enc[e]; grid 16x16 = 256 blocks = 1/CU
      gemm256_f16<<<dim3(SEQ / TM, SEQ / TN, 1), 512, 0, stream>>>(
          decF + eo, encF + eo, S, SEQ, SEQ, DDIM, DDIM, 0, 0, 0, 0);
      softmax_rows<<<SEQ, 256, 0, stream>>>(S, P);
      // out[t][d] += sum_{e in chunk z} P[t][e]*encT[d][e]; split-K z=4:
      // grid 16x4x4 = 256 blocks = 1/CU, fp32 atomic epilogue
      gemm256_f16<<<dim3(SEQ / TM, DDIM / TN, 4), 512, 0, stream>>>(
          P, encT + (size_t)b * DDIM * SEQ, out + eo, SEQ, DDIM, SEQ, SEQ / 4, SEQ / 4,
          SEQ / 4, 0, 1);
    }
  } else {
    naive_attn<<<dim3(SEQ, NBATCH), 256, 0, stream>>>(enc, dec, out);
  }
}

// Round 4
// 682.149 us; speedup vs baseline: 1.2070x; 1.0878x over previous
//
#include <hip/hip_runtime.h>
#include <hip/hip_fp16.h>

typedef _Float16 half_t;
typedef _Float16 f16x8 __attribute__((ext_vector_type(8)));
typedef _Float16 f16x4 __attribute__((ext_vector_type(4)));
typedef float f32x4 __attribute__((ext_vector_type(4)));
typedef __attribute__((address_space(3))) half_t* lds_p;

#define SEQ 4096
#define DDIM 1024
#define NBATCH 4

// async global->LDS, 16B per lane. LDS dest is wave-uniform base + lane*16,
// so the per-lane lds pointer MUST be base + lane*16 in wave-lane order.
__device__ __forceinline__ void gload16(const half_t* g, half_t* l) {
  __builtin_amdgcn_global_load_lds((const __attribute__((address_space(1))) void*)g,
                                   (__attribute__((address_space(3))) void*)l, 16, 0, 0);
}

// asm ds_read_b128: opaque to SIInsertWaitcnts, so the compiler cannot insert
// a vmcnt(0) drain before it (the R1-R3 serializer: runtime-indexed dbuf made
// the DMA->ds_read alias unprovable). Caller hand-places s_waitcnt lgkmcnt(0)
// + sched_barrier(0) before consuming (guide rule #18).
__device__ __forceinline__ f16x8 ds_read128(lds_p p) {
  f16x8 r;
  asm volatile("ds_read_b128 %0, %1" : "=v"(r) : "v"(p));
  return r;
}

// ---------------- fp32 -> fp16 elementwise convert ----------------
__global__ __launch_bounds__(256) void conv_f16(const float* __restrict__ src,
                                                half_t* __restrict__ dst) {
  int i = blockIdx.x * 256 + threadIdx.x;
  float4 x = ((const float4*)src)[i];
  f16x4 o = {(half_t)x.x, (half_t)x.y, (half_t)x.z, (half_t)x.w};
  *(f16x4*)(dst + (size_t)i * 4) = o;
}

// ------- enc [b][e][d] fp32 -> encF [b][e][d] f16 AND encT [b][d][e] f16 ----
__global__ __launch_bounds__(256) void transconv_f16(const float* __restrict__ src,
                                                     half_t* __restrict__ dstF,
                                                     half_t* __restrict__ dstT) {
  __shared__ float tile[32][33];
  int b = blockIdx.z;
  int e0 = blockIdx.x * 32, d0 = blockIdx.y * 32;
  const float* s = src + (size_t)b * SEQ * DDIM;
  half_t* df = dstF + (size_t)b * SEQ * DDIM;
  half_t* dt = dstT + (size_t)b * DDIM * SEQ;
  int tx = threadIdx.x & 31, ty = threadIdx.x >> 5;
#pragma unroll
  for (int i = 0; i < 4; i++) {
    int e = e0 + ty + i * 8;
    float v = s[(size_t)e * DDIM + d0 + tx];
    tile[ty + i * 8][tx] = v;
    df[(size_t)e * DDIM + d0 + tx] = (half_t)v;
  }
  __syncthreads();
#pragma unroll
  for (int i = 0; i < 4; i++) {
    int d = d0 + ty + i * 8;
    dt[(size_t)d * SEQ + e0 + tx] = (half_t)tile[tx][ty + i * 8];
  }
}

// ------------- fp16 BT GEMM, 256x256 tile: C[M][N] = A[M][K] * B[N][K]^T ----
// R4: TRUE 2-phase pipeline (T3 minimum recipe, m230/m248: ~655-682 TF at
// this geometry). R3 post-mortem: per-K-step was 13.1k cyc vs ~4.5k of work,
// and dbuf(R2) ~= single-buf(R1) -> compiler was draining vmcnt(0) BEFORE
// the ds_reads (runtime-indexed dbuf defeats its DMA/LDS alias analysis).
// This version: asm ds_read_b128 (opaque to waitcnt insertion), hand-placed
// s_waitcnt lgkmcnt(0)+sched_barrier(0) before MFMA (rule #18), raw s_barrier
// with hand-placed s_waitcnt vmcnt(0) AFTER the MFMAs -> next-tile loads stay
// in flight across the whole compute phase.
// Sync audit (one barrier/K-step is sound): at barrier exit each wave has
// drained its own DMA (vmcnt 0) and its ds_reads (lgkmcnt 0 pre-MFMA), so
// buf^1 is fully written and buf is dead -> DMA overwrite next iter is safe.
// 512 thr = 8 waves (2Mx4N), per-wave 128x64 (8x4 16x16 frags), LDS 128 KiB,
// grid exactly 1 block/CU. XOR chunk swizzle: bank conflicts measured 0.
// blockIdx.z: batch (sA/sB/sC strides) OR split-K chunk (atom=1 -> fp32
// atomic-add epilogue).
#define TM 256
#define TN 256
#define TK 64

__global__ __launch_bounds__(512, 2) void gemm256_p2(const half_t* __restrict__ A,
                                                     const half_t* __restrict__ B,
                                                     float* __restrict__ C, int M, int N,
                                                     int K, int kc, long sA, long sB, long sC,
                                                     int atom) {
  A += (size_t)blockIdx.z * (size_t)sA;
  B += (size_t)blockIdx.z * (size_t)sB;
  C += (size_t)blockIdx.z * (size_t)sC;
  __shared__ __align__(16) half_t As[2][TM * TK];
  __shared__ __align__(16) half_t Bs[2][TN * TK];
  const int tid = threadIdx.x;
  const int wave = tid >> 6, lane = tid & 63;
  const int wm = (wave >> 2) * 128, wn = (wave & 3) * 64;  // 2x4 wave grid
  const int mrow = lane & 15, quad = lane >> 4;

  f32x4 acc[8][4];
#pragma unroll
  for (int i = 0; i < 8; i++)
#pragma unroll
    for (int j = 0; j < 4; j++) acc[i][j] = {0.f, 0.f, 0.f, 0.f};

  const half_t* Ag = A + (size_t)(blockIdx.x * TM) * K;
  const half_t* Bg = B + (size_t)(blockIdx.y * TN) * K;
  lds_p As3 = (lds_p)&As[0][0];
  lds_p Bs3 = (lds_p)&Bs[0][0];

  // staging: tile = 256 rows x 8 chunks(16B) = 32KiB each of A,B per K-step.
  // cid = i*512 + tid; row = cid>>3, slot = cid&7, global chunk = slot^(row&7).
  // LDS dest = base + cid*16B: lane-contiguous (global_load_lds requirement).
  auto stage = [&](int buf, int k0) {
#pragma unroll
    for (int i = 0; i < 4; i++) {
      int cid = i * 512 + tid;
      int row = cid >> 3, slot = cid & 7;
      int chunk = slot ^ (row & 7);
      gload16(Ag + (size_t)row * K + k0 + chunk * 8, &As[buf][row * TK + slot * 8]);
      gload16(Bg + (size_t)row * K + k0 + chunk * 8, &Bs[buf][row * TK + slot * 8]);
    }
  };

  const int nt = kc / TK;
  stage(0, 0);
  asm volatile("s_waitcnt vmcnt(0)" ::: "memory");
  __builtin_amdgcn_s_barrier();
  int cur = 0;
  for (int t = 0; t < nt; ++t) {
    if (t + 1 < nt) stage(cur ^ 1, (t + 1) * TK);  // in flight across compute
    lds_p Ab = As3 + cur * (TM * TK);
    lds_p Bb = Bs3 + cur * (TN * TK);
#pragma unroll
    for (int ks = 0; ks < 2; ks++) {
      f16x8 af[8], bf[4];
#pragma unroll
      for (int i = 0; i < 8; i++) {
        int ra = wm + i * 16 + mrow;
        int sa = (ks * 4 + quad) ^ (ra & 7);
        af[i] = ds_read128(Ab + ra * TK + sa * 8);
      }
#pragma unroll
      for (int j = 0; j < 4; j++) {
        int rb = wn + j * 16 + mrow;
        int sb = (ks * 4 + quad) ^ (rb & 7);
        bf[j] = ds_read128(Bb + rb * TK + sb * 8);
      }
      asm volatile("s_waitcnt lgkmcnt(0)" ::: "memory");
      __builtin_amdgcn_sched_barrier(0);  // rule #18: keep MFMA below the wait
#pragma unroll
      for (int mi = 0; mi < 8; mi++)
#pragma unroll
        for (int ni = 0; ni < 4; ni++)
          acc[mi][ni] =
              __builtin_amdgcn_mfma_f32_16x16x32_f16(af[mi], bf[ni], acc[mi][ni], 0, 0, 0);
    }
    // drain ONLY here (after compute): next-tile DMA must be complete before
    // the barrier that publishes buf^1 / frees buf.
    asm volatile("s_waitcnt vmcnt(0)" ::: "memory");
    __builtin_amdgcn_s_barrier();
    cur ^= 1;
  }
  // epilogue: D[row=(quad*4+r)][col=lane&15] per 16x16 tile [m89/m91]
#pragma unroll
  for (int mi = 0; mi < 8; mi++) {
#pragma unroll
    for (int ni = 0; ni < 4; ni++) {
      int row0 = blockIdx.x * TM + wm + mi * 16 + quad * 4;
      int col = blockIdx.y * TN + wn + ni * 16 + mrow;
      float* Cp = C + (size_t)row0 * N + col;
      if (atom) {
#pragma unroll
        for (int r = 0; r < 4; r++) unsafeAtomicAdd(Cp + (size_t)r * N, acc[mi][ni][r]);
      } else {
#pragma unroll
        for (int r = 0; r < 4; r++) Cp[(size_t)r * N] = acc[mi][ni][r];
      }
    }
  }
}

// ---------------- row softmax: S[row][:] fp32 -> P[row][:] fp16 ----------------
__global__ __launch_bounds__(256) void softmax_rows(const float* __restrict__ S,
                                                    half_t* __restrict__ P) {
  const int row = blockIdx.x;
  const float4* Sr = (const float4*)(S + (size_t)row * SEQ);
  const int tid = threadIdx.x, lane = tid & 63, wave = tid >> 6;
  __shared__ float red[4];
  __shared__ float bc;
  float4 v[4];
  float m = -1e30f;
#pragma unroll
  for (int j = 0; j < 4; j++) {
    v[j] = Sr[tid + j * 256];
    m = fmaxf(m, fmaxf(fmaxf(v[j].x, v[j].y), fmaxf(v[j].z, v[j].w)));
  }
#pragma unroll
  for (int o = 32; o; o >>= 1) m = fmaxf(m, __shfl_xor(m, o));
  if (lane == 0) red[wave] = m;
  __syncthreads();
  if (tid == 0) bc = fmaxf(fmaxf(red[0], red[1]), fmaxf(red[2], red[3]));
  __syncthreads();
  m = bc;
  float s = 0.f;
#pragma unroll
  for (int j = 0; j < 4; j++) {
    v[j].x = __expf(v[j].x - m);
    v[j].y = __expf(v[j].y - m);
    v[j].z = __expf(v[j].z - m);
    v[j].w = __expf(v[j].w - m);
    s += v[j].x + v[j].y + v[j].z + v[j].w;
  }
#pragma unroll
  for (int o = 32; o; o >>= 1) s += __shfl_xor(s, o);
  __syncthreads();
  if (lane == 0) red[wave] = s;
  __syncthreads();
  if (tid == 0) bc = red[0] + red[1] + red[2] + red[3];
  __syncthreads();
  float r = 1.0f / bc;
  f16x4* Pr = (f16x4*)(P + (size_t)row * SEQ);
#pragma unroll
  for (int j = 0; j < 4; j++) {
    f16x4 o = {(half_t)(v[j].x * r), (half_t)(v[j].y * r), (half_t)(v[j].z * r),
               (half_t)(v[j].w * r)};
    Pr[tid + j * 256] = o;
  }
}

// ---------------- naive fp32 fallback (no workspace needed) ----------------
__global__ __launch_bounds__(256) void naive_attn(const float* __restrict__ enc,
                                                  const float* __restrict__ dec,
                                                  float* __restrict__ out) {
  const int b = blockIdx.y, t = blockIdx.x;
  const float* encb = enc + (size_t)b * SEQ * DDIM;
  const float* q = dec + ((size_t)b * SEQ + t) * DDIM;
  __shared__ float qs[DDIM];
  __shared__ float sc[SEQ];
  __shared__ float red[4];
  __shared__ float bc;
  const int tid = threadIdx.x, lane = tid & 63, wave = tid >> 6;
  for (int i = tid; i < DDIM; i += 256) qs[i] = q[i];
  __syncthreads();
  for (int e = tid; e < SEQ; e += 256) {
    const float* er = encb + (size_t)e * DDIM;
    float s = 0.f;
    for (int d = 0; d < DDIM; d += 4) {
      float4 ev = *(const float4*)(er + d);
      s += ev.x * qs[d] + ev.y * qs[d + 1] + ev.z * qs[d + 2] + ev.w * qs[d + 3];
    }
    sc[e] = s;
  }
  __syncthreads();
  float m = -1e30f;
  for (int e = tid; e < SEQ; e += 256) m = fmaxf(m, sc[e]);
#pragma unroll
  for (int o = 32; o; o >>= 1) m = fmaxf(m, __shfl_xor(m, o));
  if (lane == 0) red[wave] = m;
  __syncthreads();
  if (tid == 0) bc = fmaxf(fmaxf(red[0], red[1]), fmaxf(red[2], red[3]));
  __syncthreads();
  m = bc;
  float s = 0.f;
  for (int e = tid; e < SEQ; e += 256) {
    float p = __expf(sc[e] - m);
    sc[e] = p;
    s += p;
  }
#pragma unroll
  for (int o = 32; o; o >>= 1) s += __shfl_xor(s, o);
  __syncthreads();
  if (lane == 0) red[wave] = s;
  __syncthreads();
  if (tid == 0) bc = red[0] + red[1] + red[2] + red[3];
  __syncthreads();
  const float rinv = 1.0f / bc;
  const int d0 = tid * 4;
  float4 acc = {0.f, 0.f, 0.f, 0.f};
  for (int e = 0; e < SEQ; e++) {
    float p = sc[e];
    float4 ev = *(const float4*)(encb + (size_t)e * DDIM + d0);
    acc.x += p * ev.x;
    acc.y += p * ev.y;
    acc.z += p * ev.z;
    acc.w += p * ev.w;
  }
  float4* o4 = (float4*)(out + ((size_t)b * SEQ + t) * DDIM + d0);
  float4 res = {acc.x * rinv, acc.y * rinv, acc.z * rinv, acc.w * rinv};
  *o4 = res;
}

extern "C" void kernel_launch(void* const* d_in, const int* in_sizes, int n_in, void* d_out,
                              int out_size, void* d_ws, size_t ws_size, hipStream_t stream) {
  const float* enc = (const float*)d_in[0];
  const float* dec = (const float*)d_in[1];
  float* out = (float*)d_out;

  const size_t SZ_S = (size_t)SEQ * SEQ * 4;            // 64 MiB (one batch)
  const size_t SZ_P = (size_t)SEQ * SEQ * 2;            // 32 MiB (one batch)
  const size_t SZ_H = (size_t)NBATCH * SEQ * DDIM * 2;  // 32 MiB each
  const size_t NEED = SZ_S + SZ_P + 3 * SZ_H;           // 192 MiB (proven R0-R3)

  const int nconv = NBATCH * SEQ * DDIM / 4 / 256;  // 16384 blocks

  if (ws_size >= NEED) {
    char* w = (char*)d_ws;
    float* S = (float*)w;
    half_t* P = (half_t*)(w + SZ_S);
    half_t* decF = (half_t*)(w + SZ_S + SZ_P);
    half_t* encF = (half_t*)(w + SZ_S + SZ_P + SZ_H);
    half_t* encT = (half_t*)(w + SZ_S + SZ_P + 2 * SZ_H);

    hipMemsetAsync(out, 0, (size_t)NBATCH * SEQ * DDIM * 4, stream);
    conv_f16<<<nconv, 256, 0, stream>>>(dec, decF);
    transconv_f16<<<dim3(SEQ / 32, DDIM / 32, NBATCH), 256, 0, stream>>>(enc, encF, encT);

    for (int b = 0; b < NBATCH; b++) {
      const size_t eo = (size_t)b * SEQ * DDIM;
      // S[t][e] = dec[t]·enc[e]; grid 16x16 = 256 blocks = 1/CU
      gemm256_p2<<<dim3(SEQ / TM, SEQ / TN, 1), 512, 0, stream>>>(
          decF + eo, encF + eo, S, SEQ, SEQ, DDIM, DDIM, 0, 0, 0, 0);
      softmax_rows<<<SEQ, 256, 0, stream>>>(S, P);
      // out[t][d] += sum_{e in chunk z} P[t][e]*encT[d][e]; split-K z=4:
      // grid 16x4x4 = 256 blocks = 1/CU, fp32 atomic epilogue
      gemm256_p2<<<dim3(SEQ / TM, DDIM / TN, 4), 512, 0, stream>>>(
          P, encT + (size_t)b * DDIM * SEQ, out + eo, SEQ, DDIM, SEQ, SEQ / 4, SEQ / 4,
          SEQ / 4, 0, 1);
    }
  } else {
    naive_attn<<<dim3(SEQ, NBATCH), 256, 0, stream>>>(enc, dec, out);
  }
}